// Round 12
// baseline (3691.502 us; speedup 1.0000x reference)
//
#include <hip/hip_runtime.h>
#include <hip/hip_bf16.h>

static constexpr int H_ = 1024;
static constexpr int W_ = 1024;
static constexpr int STR_ = 16;
static constexpr int NH_ = 63;
static constexpr int NPATCH_ = NH_ * NH_;  // 3969

typedef short bf16x8 __attribute__((ext_vector_type(8)));
typedef short short4v __attribute__((ext_vector_type(4)));
typedef float f32x4 __attribute__((ext_vector_type(4)));

// ---------------------------------------------------------------------------
// R12: WORKSPACE-ADAPTIVE DE-FUSE. R11's fallback fired (ws < 333MB) -- the
// de-fused theory is UNTESTED. This version needs only h2 (52KB/patch):
//   K12 = patchify + conv1(LDS 40KB) + conv2 -> h2 global     (4 blocks/CU)
//   K3E = h2 -> LDS, deconv2, wave-local scratch transpose,
//         epilogue GEMM, recon atomics                        (2 blocks/CU)
// h1/h3 never exist in memory (conv1 output stays in LDS; deconv2 output
// goes reg->1KB wave scratch->epilogue A-frag). Patches processed in groups
// of ppg = ws_avail/53248, G=ceil(3969/ppg) chunks x {K12,K3E}. ppg>=100
// (ws >= ~5.6MB) else proven R9 fused fallback (1338us).
// ---------------------------------------------------------------------------
static constexpr size_t FRAG_BYTES = 212992;
static constexpr size_t H2_SLAB    = 53248;          // 16B-aligned slab

__device__ __forceinline__ unsigned short f2bf(float x) {
    __hip_bfloat16 b = __float2bfloat16(x);
    return __builtin_bit_cast(unsigned short, b);
}

__device__ __forceinline__ f32x4 mfma_bf16(bf16x8 a, bf16x8 b, f32x4 c) {
    return __builtin_amdgcn_mfma_f32_16x16x32_bf16(a, b, c, 0, 0, 0);
}

__device__ __forceinline__ float elu_neg(float x) { return __expf(x) - 1.f; }

// ============================================================================
// K12: patchify + conv1 (LDS-resident) + conv2 -> h2 (group-local slabs).
// LDS 40256B: sH1 [0,30000) gap16 [30000,30016) CP0 [30016,35136) CP1 [35136,40256)
// 512 thr (8 waves); 4 blocks/CU.
// ============================================================================
__global__ __launch_bounds__(512) void k12(
    const float* __restrict__ x1, const float* __restrict__ x2,
    const float* __restrict__ c1b, const float* __restrict__ c2b,
    const unsigned short* __restrict__ w1frag,
    const unsigned short* __restrict__ w2frag,
    unsigned short* __restrict__ h2, int p0)
{
    __shared__ alignas(16) char sbuf[40256];
    const int n = p0 + (int)blockIdx.x;
    const int t = (int)threadIdx.x;
    const int pi = n / NH_, pj = n % NH_;
    const int Y0 = pi * STR_, X0 = pj * STR_;
    const int wv = t >> 6, lane = t & 63;
    const int ln15 = lane & 15, quad = lane >> 4;

    bf16x8 w1b[8];
    #pragma unroll
    for (int g = 0; g < 8; ++g)
        w1b[g] = *(const bf16x8*)(w1frag + (g * 64 + lane) * 8);

    // ---- patchify: [2][32][40] bf16, two parity copies; zero sH1 gap ----
    if (t < 4) ((float*)(sbuf + 30000))[t] = 0.f;
    for (int k = t; k < 2048; k += 512) {
        int d = k >> 10, r = k & 1023, y = r >> 5, x = r & 31;
        unsigned short bb = f2bf((d ? x2 : x1)[(Y0 + y) * W_ + (X0 + x)]);
        int row = (d * 32 + y) * 40;
        ((unsigned short*)(sbuf + 30016))[row + x] = bb;
        if (x > 0) ((unsigned short*)(sbuf + 35136))[row + x - 1] = bb;
    }
    __syncthreads();

    // ---- conv1: M=625 (40 mtiles / 8 waves = 5), N=32, K=128, swapped MFMA ----
    {
        const f32x4 c1bq0 = *(const f32x4*)(c1b + quad * 4);
        f32x4 c1bq1 = (f32x4){0.f, 0.f, 0.f, 0.f};
        if (quad < 2) c1bq1 = *(const f32x4*)(c1b + 16 + quad * 4);
        for (int tl = wv; tl < 40; tl += 8) {
            const int rawm = tl * 16 + ln15;
            int m = rawm > 624 ? 624 : rawm;
            int u = m / 25, v = m - u * 25;
            const char* cps = sbuf + ((v & 1) ? 35136 : 30016);
            const int vb2 = (v & ~1) * 2;
            f32x4 acc0 = (f32x4){0.f, 0.f, 0.f, 0.f};
            f32x4 acc1 = (f32x4){0.f, 0.f, 0.f, 0.f};
            #pragma unroll
            for (int kc = 0; kc < 4; ++kc) {
                const int idx8 = kc * 4 + quad;
                const int dd = idx8 >> 3, pp = idx8 & 7;
                const unsigned int* ap = (const unsigned int*)(cps + (dd * 32 + u + pp) * 80 + vb2);
                union { unsigned int u4[4]; bf16x8 v8; } af;
                af.u4[0] = ap[0]; af.u4[1] = ap[1]; af.u4[2] = ap[2]; af.u4[3] = ap[3];
                acc0 = mfma_bf16(w1b[kc * 2 + 0], af.v8, acc0);   // swapped
                acc1 = mfma_bf16(w1b[kc * 2 + 1], af.v8, acc1);
            }
            if (rawm < 625) {
                char* rowp = sbuf + rawm * 48;
                short4v p0v;
                #pragma unroll
                for (int r = 0; r < 4; ++r) {
                    float hv = acc0[r] + c1bq0[r];
                    hv = hv > 0.f ? hv : elu_neg(hv);
                    p0v[r] = (short)f2bf(hv);
                }
                *(short4v*)(rowp + quad * 8) = p0v;
                if (quad < 2) {
                    short4v p1v;
                    #pragma unroll
                    for (int r = 0; r < 4; ++r) {
                        float hw = acc1[r] + c1bq1[r];
                        hw = hw > 0.f ? hw : elu_neg(hw);
                        p1v[r] = (short)f2bf(hw);
                    }
                    *(short4v*)(rowp + 32 + quad * 8) = p1v;
                }
            }
        }
    }
    __syncthreads();

    // ---- conv2: M=441 (28 mtiles / 8 waves), N=64, K=32; write h2 global ----
    {
        const unsigned short* wb = w2frag + lane * 8;
        unsigned short* h2g = h2 + (size_t)blockIdx.x * (H2_SLAB / 2);
        for (int mt = wv; mt < 28; mt += 8) {
            int mm = mt * 16 + ln15; if (mm > 440) mm = 440;
            int y = mm / 21, x = mm - y * 21;
            const int abase = (y * 25 + x) * 48;
            f32x4 acc[4];
            #pragma unroll
            for (int nt = 0; nt < 4; ++nt) acc[nt] = (f32x4){0.f, 0.f, 0.f, 0.f};
            #pragma unroll
            for (int p = 0; p < 5; ++p) {
                #pragma unroll
                for (int q = 0; q < 5; ++q) {
                    const int tap  = p * 5 + q;
                    const int toff = (p * 25 + q) * 48;
                    bf16x8 bfr[4];
                    #pragma unroll
                    for (int nt = 0; nt < 4; ++nt)
                        bfr[nt] = *(const bf16x8*)(wb + (tap * 4 + nt) * 512);
                    bf16x8 a = *(const bf16x8*)(sbuf + abase + toff + quad * 16);
                    #pragma unroll
                    for (int nt = 0; nt < 4; ++nt)
                        acc[nt] = mfma_bf16(bfr[nt], a, acc[nt]);   // swapped
                }
            }
            int rawpix = mt * 16 + ln15;
            if (rawpix < 441) {
                unsigned short* rowp = h2g + rawpix * 60;
                #pragma unroll
                for (int nt = 0; nt < 4; ++nt) {
                    if (nt == 3 && quad == 3) continue;              // ch 60..63
                    const f32x4 bq = *(const f32x4*)(c2b + nt * 16 + quad * 4);
                    short4v pk;
                    #pragma unroll
                    for (int r = 0; r < 4; ++r)
                        pk[r] = (short)f2bf(fmaxf(acc[nt][r] + bq[r], 0.f));
                    *(short4v*)(rowp + nt * 16 + quad * 4) = pk;
                }
            }
        }
    }
}

// ============================================================================
// K3E: h2 -> LDS; deconv2 (40 mtiles / 8 waves = 5); elu -> 1KB wave scratch
// (reg-layout transpose: ch quad*4+r -> ch quad*8+j); epilogue GEMM; LDS sp
// scatter; global overlap-add.
// LDS 70464B: sH2 [0,52920) zrow [52920,53056) scratch [53056,62272)=8x1152
//             sWc [62272,66368) sp [66368,70464).  2 blocks/CU.
// ============================================================================
__global__ __launch_bounds__(512) void k3e(
    const float* __restrict__ d2b, const float* __restrict__ d1b,
    const float* __restrict__ lin_w, const float* __restrict__ lin_b,
    const float* __restrict__ dw1,
    const unsigned short* __restrict__ dw2frag,
    const unsigned short* __restrict__ h2, float* __restrict__ recon, int p0)
{
    __shared__ alignas(16) char sbuf[70464];
    const int n = p0 + (int)blockIdx.x;
    const int t = (int)threadIdx.x;
    const int pi = n / NH_, pj = n % NH_;
    const int Y0 = pi * STR_, X0 = pj * STR_;
    const int wv = t >> 6, lane = t & 63;
    const int ln15 = lane & 15, quad = lane >> 4;
    const float lw0 = lin_w[2 * n], lw1 = lin_w[2 * n + 1];

    {   // stage h2 patch
        const f32x4* src = (const f32x4*)(h2 + (size_t)blockIdx.x * (H2_SLAB / 2));
        f32x4* dst = (f32x4*)sbuf;
        for (int i = t; i < 3307; i += 512) dst[i] = src[i];        // [0,52912)
        if (t == 511)
            *(unsigned long long*)(sbuf + 52912) =
                *(const unsigned long long*)((const char*)src + 52912);
        if (t < 17) ((unsigned long long*)(sbuf + 52920))[t] = 0ull; // zrow 136B
    }
    {   // sWc: 64r x 32c bf16 (c>=24 zero)
        unsigned short* swc = (unsigned short*)(sbuf + 62272);
        for (int k = t; k < 2048; k += 512) {
            int r = k >> 5, c = k & 31;
            float v = 0.f;
            if (c < 24)
                v = lw0 * dw1[(c * 2 + 0) * 64 + r] + lw1 * dw1[(c * 2 + 1) * 64 + r];
            swc[r * 32 + c] = f2bf(v);
        }
    }
    {   // zero sp
        float* sp = (float*)(sbuf + 66368);
        for (int k = t; k < 1024; k += 512) sp[k] = 0.f;
    }
    __syncthreads();

    const unsigned short* db = dw2frag + lane * 8;
    const f32x4 d2bq0 = *(const f32x4*)(d2b + quad * 4);
    f32x4 d2bq1 = (f32x4){0.f, 0.f, 0.f, 0.f};
    if (quad < 2) d2bq1 = *(const f32x4*)(d2b + 16 + quad * 4);
    bf16x8 wbv[4];                                   // hoisted (mt-invariant)
    #pragma unroll
    for (int nt = 0; nt < 4; ++nt)
        wbv[nt] = *(const bf16x8*)(sbuf + 62272 + (nt * 16 + ln15) * 64 + quad * 16);
    float* sp = (float*)(sbuf + 66368);
    char* scr = sbuf + 53056 + wv * 1152;            // wave-local [16 pix][72B]
    int qoff[4];
    #pragma unroll
    for (int r = 0; r < 4; ++r) {
        int qr = quad * 4 + r;
        qoff[r] = (qr >> 3) * 32 + (qr & 7);
    }

    for (int mt = wv; mt < 40; mt += 8) {
        const int m = mt * 16 + ln15;
        const bool mv = (m < 625);
        const int mc = mv ? m : 0;
        const int ua = mc / 25, va = mc - ua * 25;
        const int aoff = (ua * 21 + va) * 120;
        f32x4 accN0 = (f32x4){0.f, 0.f, 0.f, 0.f};
        f32x4 accN1 = (f32x4){0.f, 0.f, 0.f, 0.f};
        #pragma unroll
        for (int dy = 0; dy < 5; ++dy) {
            #pragma unroll
            for (int dx = 0; dx < 5; ++dx) {
                const int tap = dy * 5 + dx;
                const int t2o = (dy * 21 + dx) * 120;
                bf16x8 bc0 = *(const bf16x8*)(db + tap * 2048);
                bf16x8 bc1 = *(const bf16x8*)(db + tap * 2048 + 512);
                bf16x8 bc2 = *(const bf16x8*)(db + tap * 2048 + 1024);
                bf16x8 bc3 = *(const bf16x8*)(db + tap * 2048 + 1536);
                int yv = ua - dy, xv = va - dx;
                bool ok = mv && ((unsigned)yv < 21u) && ((unsigned)xv < 21u);
                int ra = ok ? (aoff - t2o) : 52920;              // zero row
                const char* ap = sbuf + ra + quad * 16;
                short4v lo0 = *(const short4v*)(ap);
                short4v hi0 = *(const short4v*)(ap + 8);
                bf16x8 a0 = __builtin_shufflevector(lo0, hi0, 0, 1, 2, 3, 4, 5, 6, 7);
                accN0 = mfma_bf16(bc0, a0, accN0);               // swapped
                accN1 = mfma_bf16(bc1, a0, accN1);
                short4v lo1 = *(const short4v*)(ap + 64);
                short4v hi1 = *(const short4v*)(ap + 72);
                bf16x8 a1 = __builtin_shufflevector(lo1, hi1, 0, 1, 2, 3, 4, 5, 6, 7);
                accN0 = mfma_bf16(bc2, a1, accN0);
                accN1 = mfma_bf16(bc3, a1, accN1);
            }
        }
        // elu+bias -> wave scratch (ch 24..31 are exact zeros: zero weights+bias)
        {
            short4v p0v, p1v;
            #pragma unroll
            for (int r = 0; r < 4; ++r) {
                float hv = accN0[r] + d2bq0[r];
                hv = hv > 0.f ? hv : elu_neg(hv);
                p0v[r] = (short)f2bf(hv);
            }
            #pragma unroll
            for (int r = 0; r < 4; ++r) {
                float hw = accN1[r] + d2bq1[r];
                hw = hw > 0.f ? hw : elu_neg(hw);
                p1v[r] = (short)f2bf(hw);
            }
            *(short4v*)(scr + ln15 * 72 + quad * 8) = p0v;       // ch quad*4..+3
            *(short4v*)(scr + ln15 * 72 + 32 + quad * 8) = p1v;  // ch 16+quad*4..+3
        }
        // epilogue A-frag: lane(ln15,quad) = ch quad*8..+7 of its pixel
        bf16x8 a = *(const bf16x8*)(scr + ln15 * 72 + quad * 16);
        const int pc = mv ? m : 624;
        const int uvbase = (pc / 25) * 32 + (pc % 25);
        #pragma unroll
        for (int nt = 0; nt < 4; ++nt) {
            f32x4 a4 = (f32x4){0.f, 0.f, 0.f, 0.f};
            a4 = mfma_bf16(wbv[nt], a, a4);                      // swapped
            if (mv) {
                #pragma unroll
                for (int r = 0; r < 4; ++r)
                    atomicAdd(&sp[uvbase + nt * 64 + qoff[r]], a4[r]);
            }
        }
    }
    __syncthreads();

    const float obias = d1b[0] * (lw0 + lw1) + lin_b[n];
    for (int k = t; k < 1024; k += 512) {
        int yy = k >> 5, xx = k & 31;
        atomicAdd(&recon[(Y0 + yy) * W_ + (X0 + xx)], sp[k] + obias);
    }
}

// ============================================================================
// FALLBACK: R9 fused megakernel (proven 1338us) -- used when ws too small.
// ============================================================================
static constexpr int FGAP16 = 49200;
static constexpr int FCP0   = 49216;
static constexpr int FCP1   = 55360;
static constexpr int FSH2_0 = 49216;
static constexpr int FSH2SZ = 52920;
static constexpr int FSH2_1 = FSH2_0 + FSH2SZ;
static constexpr int FZROW  = 155056;
static constexpr int FH3SZ  = 30000;
static constexpr int FSWC0  = 60000;
static constexpr int FSWC1  = 64096;
static constexpr int FSPA   = 68192;
static constexpr int FLDS   = 155200;
static constexpr int FNGRP  = 32;
static constexpr int FNBLK  = NH_ * FNGRP;

__global__
__attribute__((amdgpu_flat_work_group_size(1024, 1024), amdgpu_waves_per_eu(4, 4)))
void fused_patch_kernel(
    const float* __restrict__ x1, const float* __restrict__ x2,
    const float* __restrict__ c1b, const float* __restrict__ c2b,
    const float* __restrict__ d2b, const float* __restrict__ d1b,
    const float* __restrict__ lin_w, const float* __restrict__ lin_b,
    const unsigned short* __restrict__ w1frag,
    const unsigned short* __restrict__ w2frag,
    const unsigned short* __restrict__ dw2frag,
    const float* __restrict__ dw1,
    float* __restrict__ recon)
{
    __shared__ alignas(16) char sbuf[FLDS];
    const int b   = blockIdx.x;
    const int pi  = b / FNGRP, g = b - pi * FNGRP;
    const int pj0 = 2 * g;
    const int npat = (pj0 + 1 < NH_) ? 2 : 1;
    const int n0  = pi * NH_ + pj0;
    const int n1  = (npat == 2) ? (n0 + 1) : n0;
    const int Y0  = pi * STR_, X0 = pj0 * STR_;
    const int t   = (int)threadIdx.x;
    const int wv  = t >> 6, lane = t & 63;
    const int ln15 = lane & 15, quad = lane >> 4;

    bf16x8 w1b[8];
    #pragma unroll
    for (int gg = 0; gg < 8; ++gg)
        w1b[gg] = *(const bf16x8*)(w1frag + (gg * 64 + lane) * 8);
    const float lw00 = lin_w[2 * n0], lw01 = lin_w[2 * n0 + 1];
    const float lw10 = lin_w[2 * n1], lw11 = lin_w[2 * n1 + 1];
    const float lbn0 = lin_b[n0], lbn1 = lin_b[n1];
    const float d1b0 = d1b[0];
    const f32x4 c1bq0 = *(const f32x4*)(c1b + quad * 4);
    f32x4 c1bq1 = (f32x4){0.f, 0.f, 0.f, 0.f};
    if (quad < 2) c1bq1 = *(const f32x4*)(c1b + 16 + quad * 4);
    const f32x4 d2bq0 = *(const f32x4*)(d2b + quad * 4);
    f32x4 d2bq1 = (f32x4){0.f, 0.f, 0.f, 0.f};
    if (quad < 2) d2bq1 = *(const f32x4*)(d2b + 16 + quad * 4);
    float dwp[4] = {0.f, 0.f, 0.f, 0.f};
    {
        int r0 = t >> 5, c0 = t & 31;
        if (c0 < 24) {
            dwp[0] = dw1[(c0 * 2 + 0) * 64 + r0];
            dwp[1] = dw1[(c0 * 2 + 1) * 64 + r0];
        }
        int k1 = t + 1024, r1 = k1 >> 5, c1 = k1 & 31;
        if (c1 < 24) {
            dwp[2] = dw1[(c1 * 2 + 0) * 64 + r1];
            dwp[3] = dw1[(c1 * 2 + 1) * 64 + r1];
        }
    }

    if (t < 4)       ((float*)(sbuf + FGAP16))[t] = 0.f;
    else if (t < 8)  ((float*)(sbuf + FSH2_1))[t - 4] = 0.f;
    else if (t < 42) ((float*)(sbuf + FZROW))[t - 8] = 0.f;
    #pragma unroll
    for (int it = 0; it < 3; ++it) {
        int k = t + it * 1024;
        int d = (k >= 1536) ? 1 : 0;
        int rem = k - d * 1536;
        int y = rem / 48, x = rem - y * 48;
        int xg = X0 + x; if (xg > W_ - 1) xg = W_ - 1;
        unsigned short bb = f2bf((d ? x2 : x1)[(Y0 + y) * W_ + xg]);
        int row = (d * 32 + y) * 48;
        ((unsigned short*)(sbuf + FCP0))[row + x] = bb;
        if (x > 0) ((unsigned short*)(sbuf + FCP1))[row + x - 1] = bb;
    }
    __syncthreads();

    for (int tl = wv; tl < 65; tl += 16) {
        const int rawm = tl * 16 + ln15;
        int m = rawm; if (m > 1024) m = 1024;
        int u = m / 41, v = m - u * 41;
        const char* cps = sbuf + ((v & 1) ? FCP1 : FCP0);
        const int vb2 = (v & ~1) * 2;
        f32x4 acc[2];
        acc[0] = (f32x4){0.f, 0.f, 0.f, 0.f};
        acc[1] = (f32x4){0.f, 0.f, 0.f, 0.f};
        #pragma unroll
        for (int kc = 0; kc < 4; ++kc) {
            const int idx8 = kc * 4 + quad;
            const int dd = idx8 >> 3, pp = idx8 & 7;
            const unsigned int* ap = (const unsigned int*)(cps + (dd * 32 + u + pp) * 96 + vb2);
            union { unsigned int u4[4]; bf16x8 v8; } af;
            af.u4[0] = ap[0]; af.u4[1] = ap[1]; af.u4[2] = ap[2]; af.u4[3] = ap[3];
            acc[0] = mfma_bf16(w1b[kc * 2 + 0], af.v8, acc[0]);
            acc[1] = mfma_bf16(w1b[kc * 2 + 1], af.v8, acc[1]);
        }
        if (rawm < 1025) {
            char* rowp = sbuf + rawm * 48;
            short4v p0;
            #pragma unroll
            for (int r = 0; r < 4; ++r) {
                float hv = acc[0][r] + c1bq0[r];
                hv = hv > 0.f ? hv : elu_neg(hv);
                p0[r] = (short)f2bf(hv);
            }
            *(short4v*)(rowp + quad * 8) = p0;
            if (quad < 2) {
                short4v p1;
                #pragma unroll
                for (int r = 0; r < 4; ++r) {
                    float hw = acc[1][r] + c1bq1[r];
                    hw = hw > 0.f ? hw : elu_neg(hw);
                    p1[r] = (short)f2bf(hw);
                }
                *(short4v*)(rowp + 32 + quad * 8) = p1;
            }
        }
    }
    __syncthreads();

    auto s2pass = [&](int t0, int t1) {
        const bool h1ok = (t1 < 56);
        int ab[2], loc[2], Pp[2];
        #pragma unroll
        for (int i = 0; i < 2; ++i) {
            int tt = i ? (h1ok ? t1 : t0) : t0;
            int P = (tt >= 28) ? 1 : 0;
            int lc = tt - P * 28;
            int mm = lc * 16 + ln15; if (mm > 440) mm = 440;
            int y = mm / 21, x = mm - y * 21;
            ab[i] = (y * 41 + P * 16 + x) * 48;
            loc[i] = lc; Pp[i] = P;
        }
        f32x4 acc2[2][4];
        #pragma unroll
        for (int i = 0; i < 2; ++i)
            #pragma unroll
            for (int nt = 0; nt < 4; ++nt)
                acc2[i][nt] = (f32x4){0.f, 0.f, 0.f, 0.f};
        const unsigned short* wb = w2frag + lane * 8;
        #pragma unroll
        for (int p = 0; p < 5; ++p) {
            #pragma unroll
            for (int q = 0; q < 5; ++q) {
                const int tap  = p * 5 + q;
                const int toff = (p * 41 + q) * 48;
                bf16x8 bfr[4];
                #pragma unroll
                for (int nt = 0; nt < 4; ++nt)
                    bfr[nt] = *(const bf16x8*)(wb + (tap * 4 + nt) * 512);
                {
                    bf16x8 a = *(const bf16x8*)(sbuf + ab[0] + toff + quad * 16);
                    #pragma unroll
                    for (int nt = 0; nt < 4; ++nt)
                        acc2[0][nt] = mfma_bf16(bfr[nt], a, acc2[0][nt]);
                }
                if (h1ok) {
                    bf16x8 a = *(const bf16x8*)(sbuf + ab[1] + toff + quad * 16);
                    #pragma unroll
                    for (int nt = 0; nt < 4; ++nt)
                        acc2[1][nt] = mfma_bf16(bfr[nt], a, acc2[1][nt]);
                }
            }
        }
        #pragma unroll
        for (int i = 0; i < 2; ++i) {
            if (i == 1 && !h1ok) continue;
            int rawpix = loc[i] * 16 + ln15;
            if (rawpix < 441) {
                char* rowp = sbuf + FSH2_0 + Pp[i] * FSH2SZ + rawpix * 120;
                #pragma unroll
                for (int nt = 0; nt < 4; ++nt) {
                    if (nt == 3 && quad == 3) continue;
                    const f32x4 bq = *(const f32x4*)(c2b + nt * 16 + quad * 4);
                    short4v pk;
                    #pragma unroll
                    for (int r = 0; r < 4; ++r)
                        pk[r] = (short)f2bf(fmaxf(acc2[i][nt][r] + bq[r], 0.f));
                    *(short4v*)(rowp + nt * 32 + quad * 8) = pk;
                }
            }
        }
    };
    s2pass(wv, wv + 16);
    s2pass(wv + 32, wv + 48);
    __syncthreads();

    f32x4 acc3[5][2];
    {
        #pragma unroll
        for (int i = 0; i < 5; ++i) {
            acc3[i][0] = (f32x4){0.f, 0.f, 0.f, 0.f};
            acc3[i][1] = (f32x4){0.f, 0.f, 0.f, 0.f};
        }
        int uarr[5], varr[5], aoff[5];
        bool mval[5];
        #pragma unroll
        for (int i = 0; i < 5; ++i) {
            int t5 = wv + 16 * i;
            int P = (t5 >= 40) ? 1 : 0;
            int lc = t5 - P * 40;
            int m = lc * 16 + ln15;
            mval[i] = (m < 625);
            int mc = mval[i] ? m : 0;
            uarr[i] = mc / 25; varr[i] = mc - uarr[i] * 25;
            aoff[i] = FSH2_0 + P * FSH2SZ + (uarr[i] * 21 + varr[i]) * 120;
        }
        const unsigned short* db = dw2frag + lane * 8;
        #pragma unroll
        for (int dy = 0; dy < 5; ++dy) {
            #pragma unroll
            for (int dx = 0; dx < 5; ++dx) {
                const int tap = dy * 5 + dx;
                const int t2o = (dy * 21 + dx) * 120;
                bf16x8 bc0 = *(const bf16x8*)(db + tap * 2048);
                bf16x8 bc1 = *(const bf16x8*)(db + tap * 2048 + 512);
                bf16x8 bc2 = *(const bf16x8*)(db + tap * 2048 + 1024);
                bf16x8 bc3 = *(const bf16x8*)(db + tap * 2048 + 1536);
                #pragma unroll
                for (int i = 0; i < 5; ++i) {
                    int yv = uarr[i] - dy, xv = varr[i] - dx;
                    bool ok = mval[i] && ((unsigned)yv < 21u) && ((unsigned)xv < 21u);
                    int ra = ok ? (aoff[i] - t2o) : FZROW;
                    const char* ap = sbuf + ra + quad * 16;
                    short4v lo0 = *(const short4v*)(ap);
                    short4v hi0 = *(const short4v*)(ap + 8);
                    bf16x8 a0 = __builtin_shufflevector(lo0, hi0, 0, 1, 2, 3, 4, 5, 6, 7);
                    acc3[i][0] = mfma_bf16(bc0, a0, acc3[i][0]);
                    acc3[i][1] = mfma_bf16(bc1, a0, acc3[i][1]);
                    short4v lo1 = *(const short4v*)(ap + 64);
                    short4v hi1 = *(const short4v*)(ap + 72);
                    bf16x8 a1 = __builtin_shufflevector(lo1, hi1, 0, 1, 2, 3, 4, 5, 6, 7);
                    acc3[i][0] = mfma_bf16(bc2, a1, acc3[i][0]);
                    acc3[i][1] = mfma_bf16(bc3, a1, acc3[i][1]);
                }
            }
        }
    }
    __syncthreads();

    float* sp = (float*)(sbuf + FSPA);
    {
        #pragma unroll
        for (int i = 0; i < 5; ++i) {
            int t5 = wv + 16 * i;
            int P = (t5 >= 40) ? 1 : 0;
            int lc = t5 - P * 40;
            int pix = lc * 16 + ln15;
            if (pix < 625) {
                char* rowp = sbuf + P * FH3SZ + pix * 48;
                short4v p0;
                #pragma unroll
                for (int r = 0; r < 4; ++r) {
                    float hv = acc3[i][0][r] + d2bq0[r];
                    hv = hv > 0.f ? hv : elu_neg(hv);
                    p0[r] = (short)f2bf(hv);
                }
                *(short4v*)(rowp + quad * 8) = p0;
                if (quad < 2) {
                    short4v p1;
                    #pragma unroll
                    for (int r = 0; r < 4; ++r) {
                        float hw = acc3[i][1][r] + d2bq1[r];
                        hw = hw > 0.f ? hw : elu_neg(hw);
                        p1[r] = (short)f2bf(hw);
                    }
                    *(short4v*)(rowp + 32 + quad * 8) = p1;
                }
            }
        }
    }
    {
        int r0 = t >> 5, c0 = t & 31;
        ((unsigned short*)(sbuf + FSWC0))[r0 * 32 + c0] = f2bf(lw00 * dwp[0] + lw01 * dwp[1]);
        ((unsigned short*)(sbuf + FSWC1))[r0 * 32 + c0] = f2bf(lw10 * dwp[0] + lw11 * dwp[1]);
        int k1 = t + 1024, r1 = k1 >> 5, c1 = k1 & 31;
        ((unsigned short*)(sbuf + FSWC0))[r1 * 32 + c1] = f2bf(lw00 * dwp[2] + lw01 * dwp[3]);
        ((unsigned short*)(sbuf + FSWC1))[r1 * 32 + c1] = f2bf(lw10 * dwp[2] + lw11 * dwp[3]);
    }
    sp[t] = 0.f; sp[t + 1024] = 0.f;
    __syncthreads();

    {
        int qoff[4];
        #pragma unroll
        for (int r = 0; r < 4; ++r) {
            int qr = quad * 4 + r;
            qoff[r] = (qr >> 3) * 32 + (qr & 7);
        }
        #pragma unroll
        for (int i = 0; i < 5; ++i) {
            int t5 = wv + 16 * i;
            int P = (t5 >= 40) ? 1 : 0;
            int lc = t5 - P * 40;
            int rawpix = lc * 16 + ln15;
            bool pok = (rawpix < 625);
            int pc = pok ? rawpix : 624;
            bf16x8 a = *(const bf16x8*)(sbuf + P * FH3SZ + pc * 48 + quad * 16);
            const char* swc = sbuf + (P ? FSWC1 : FSWC0);
            float* spP = sp + P * 1024;
            int uvbase = (pc / 25) * 32 + (pc % 25);
            #pragma unroll
            for (int nt = 0; nt < 4; ++nt) {
                bf16x8 wbv = *(const bf16x8*)(swc + (nt * 16 + ln15) * 64 + quad * 16);
                f32x4 acc4 = (f32x4){0.f, 0.f, 0.f, 0.f};
                acc4 = mfma_bf16(wbv, a, acc4);
                if (pok) {
                    #pragma unroll
                    for (int r = 0; r < 4; ++r)
                        atomicAdd(&spP[uvbase + nt * 64 + qoff[r]], acc4[r]);
                }
            }
        }
    }
    __syncthreads();

    {
        int yy = t >> 5, xx = t & 31;
        float ob0 = d1b0 * (lw00 + lw01) + lbn0;
        atomicAdd(&recon[(Y0 + yy) * W_ + X0 + xx], sp[t] + ob0);
        if (npat == 2) {
            float ob1 = d1b0 * (lw10 + lw11) + lbn1;
            atomicAdd(&recon[(Y0 + yy) * W_ + X0 + 16 + xx], sp[t + 1024] + ob1);
        }
    }
}

// ---------------------------------------------------------------------------
__global__ void prep_kernel(const float* __restrict__ c1w,
                            const float* __restrict__ c2w,
                            const float* __restrict__ d2w,
                            unsigned short* __restrict__ w1frag,
                            unsigned short* __restrict__ w2frag,
                            unsigned short* __restrict__ dw2frag)
{
    int i = blockIdx.x * blockDim.x + threadIdx.x;
    if (i < 51200) {
        int j = i & 7, lane = (i >> 3) & 63;
        int ln15 = lane & 15, quad = lane >> 4;
        if (i < 4096) {   // conv1
            int g = i >> 9;
            int kc = g >> 1, nt = g & 1;
            int nn = nt * 16 + ln15, k = kc * 32 + quad * 8 + j;
            w1frag[i] = f2bf((nn < 24) ? c1w[nn * 128 + k] : 0.f);
        }
        {   // conv2
            int nt = (i >> 9) & 3, tap = i >> 11;
            int o = nt * 16 + ln15, c = quad * 8 + j;
            float v = (o < 60 && c < 24) ? c2w[(o * 24 + c) * 25 + tap] : 0.f;
            w2frag[i] = f2bf(v);
        }
        {   // deconv2
            int nt = (i >> 9) & 1, kc = (i >> 10) & 1, tap = i >> 11;
            int k = kc * 32 + quad * 8 + j, c = nt * 16 + ln15;
            float v = (k < 60 && c < 24) ? d2w[(k * 24 + c) * 25 + tap] : 0.f;
            dw2frag[i] = f2bf(v);
        }
    }
}

__global__ void finalize_kernel(const float* __restrict__ x2,
                                const float* __restrict__ l1w,
                                float* __restrict__ out)
{
    int i = blockIdx.x * blockDim.x + threadIdx.x;
    if (i < H_ * W_) {
        float r = out[i];
        out[i] = x2[i] - r * l1w[0];
    }
}

extern "C" void kernel_launch(void* const* d_in, const int* in_sizes, int n_in,
                              void* d_out, int out_size, void* d_ws, size_t ws_size,
                              hipStream_t stream)
{
    const float* x1  = (const float*)d_in[0];
    const float* x2  = (const float*)d_in[1];
    const float* c1w = (const float*)d_in[2];
    const float* c1b = (const float*)d_in[3];
    const float* c2w = (const float*)d_in[4];
    const float* c2b = (const float*)d_in[5];
    const float* d2w = (const float*)d_in[6];
    const float* d2b = (const float*)d_in[7];
    const float* d1w = (const float*)d_in[8];
    const float* d1b = (const float*)d_in[9];
    const float* lw  = (const float*)d_in[10];
    const float* lb  = (const float*)d_in[11];
    const float* l1w = (const float*)d_in[12];

    float*          out     = (float*)d_out;
    unsigned short* w1frag  = (unsigned short*)d_ws;                      // 8192 B
    unsigned short* w2frag  = (unsigned short*)((char*)d_ws + 8192);      // 102400 B
    unsigned short* dw2frag = (unsigned short*)((char*)d_ws + 110592);    // 102400 B

    hipMemsetAsync(d_out, 0, (size_t)H_ * W_ * sizeof(float), stream);
    prep_kernel<<<100, 512, 0, stream>>>(c1w, c2w, d2w, w1frag, w2frag, dw2frag);

    size_t avail = (ws_size > FRAG_BYTES) ? (ws_size - FRAG_BYTES) : 0;
    size_t ppg_s = avail / H2_SLAB;
    int ppg = (ppg_s > (size_t)NPATCH_) ? NPATCH_ : (int)ppg_s;

    if (ppg >= 100) {
        unsigned short* h2 = (unsigned short*)((char*)d_ws + FRAG_BYTES);
        for (int p0 = 0; p0 < NPATCH_; p0 += ppg) {
            int cnt = NPATCH_ - p0; if (cnt > ppg) cnt = ppg;
            k12<<<cnt, 512, 0, stream>>>(x1, x2, c1b, c2b, w1frag, w2frag, h2, p0);
            k3e<<<cnt, 512, 0, stream>>>(d2b, d1b, lw, lb, d1w, dw2frag, h2, out, p0);
        }
    } else {
        fused_patch_kernel<<<FNBLK, 1024, 0, stream>>>(x1, x2, c1b, c2b, d2b, d1b,
                                                       lw, lb, w1frag, w2frag, dw2frag,
                                                       d1w, out);
    }
    finalize_kernel<<<(H_ * W_ + 255) / 256, 256, 0, stream>>>(x2, l1w, out);
}

// Round 13
// 1342.698 us; speedup vs baseline: 2.7493x; 2.7493x over previous
//
#include <hip/hip_runtime.h>
#include <hip/hip_bf16.h>

static constexpr int H_ = 1024;
static constexpr int W_ = 1024;
static constexpr int STR_ = 16;
static constexpr int NH_ = 63;
static constexpr int NPATCH_ = NH_ * NH_;  // 3969

typedef short bf16x8 __attribute__((ext_vector_type(8)));
typedef short short4v __attribute__((ext_vector_type(4)));
typedef float f32x4 __attribute__((ext_vector_type(4)));
typedef float f32x16 __attribute__((ext_vector_type(16)));

// ---------------------------------------------------------------------------
// R13 = R9 (best, 1337.8us) + S3 rewritten with 32x32x16 MFMA.
// Evidence basis: R12 de-fuse failed (HBM-bound on L2-evicted weight refetch;
// k12 alone ~1.3ms -> barriers never were the bottleneck). Wins only ever came
// from SHORTENING the instruction stream (R3 VALU 1:1, R8 spills 1:1).
// S3 (deconv2, largest phase) instruction stream ~45% shorter via shape swap:
//   per 32 output rows per tap: 4 MFMA (was 8), 4 ds_read_b128 (was 8 b64),
//   1 validity check (was 2).
// Supporting changes:
//   - sH2 stride 120 -> 128B; XOR-swizzle (key = abs_addr>>7 & 7, applied
//     identically on S2-write and S3-read; pow2 stride would otherwise be a
//     32-way bank conflict).
//   - S2 writes bytes [120,128) of each row as ZERO (k=60..63 pad; NaN*0
//     hazard -- R0 lesson).
//   - dw2frag repacked for 32x32x16 instr-A: c = lane&31, k = ks*16+(lane>>5)*8+j.
//   - S4a rewritten for 32x32 D layout: pixel = lane&31,
//     c = (reg&3)+8*(reg>>2)+4*(lane>>5); 3x b64 stores/lane.
//
// LDS (bytes), total 162320 (<= 160KiB = 163840; 1 block/CU):
//   sH1:   [0, 49200)        1025 rows x 48B (union conv1 grid 25x41)
//   gap16: [49200, 49216)    ZEROED in S0 (S2 quad3 overread of sH1 row 1024)
//   pad:   [49216, 49280)    unused (128-align sH2_0)
//   sH2_0: [49280, 105728)   441 rows x 128B, swizzled
//   sH2_1: [105728, 162176)  441 rows x 128B; head 16B ZEROED in S0
//   zrow:  [162176, 162312)  ZEROED in S0 (S3 invalid-tap reads, 128B reach)
//   CP0:   [49280, 55424)  CP1: [55424, 61568)   patch stage (dead before S2 wr)
//   After S3: h3_0 [0,30000) h3_1 [30000,60000); sWc0/1 [60000/64096,+4096);
//             sp [68192,76384) 2x1024 f32
// ---------------------------------------------------------------------------
static constexpr int FGAP16 = 49200;
static constexpr int FCP0   = 49280;
static constexpr int FCP1   = 55424;
static constexpr int FSH2_0 = 49280;
static constexpr int FSH2SZ = 56448;            // 441 * 128
static constexpr int FSH2_1 = FSH2_0 + FSH2SZ;  // 105728
static constexpr int FZROW  = 162176;           // 128-aligned
static constexpr int FH3SZ  = 30000;
static constexpr int FSWC0  = 60000;
static constexpr int FSWC1  = 64096;
static constexpr int FSPA   = 68192;
static constexpr int FLDS   = 162320;
static constexpr int FNGRP  = 32;
static constexpr int FNBLK  = NH_ * FNGRP;      // 2016

__device__ __forceinline__ unsigned short f2bf(float x) {
    __hip_bfloat16 b = __float2bfloat16(x);
    return __builtin_bit_cast(unsigned short, b);
}

__device__ __forceinline__ f32x4 mfma_bf16(bf16x8 a, bf16x8 b, f32x4 c) {
    return __builtin_amdgcn_mfma_f32_16x16x32_bf16(a, b, c, 0, 0, 0);
}

__device__ __forceinline__ f32x16 mfma32_bf16(bf16x8 a, bf16x8 b, f32x16 c) {
    return __builtin_amdgcn_mfma_f32_32x32x16_bf16(a, b, c, 0, 0, 0);
}

__device__ __forceinline__ float elu_neg(float x) { return __expf(x) - 1.f; }

__global__
__attribute__((amdgpu_flat_work_group_size(1024, 1024), amdgpu_waves_per_eu(4, 4)))
void fused_patch_kernel(
    const float* __restrict__ x1, const float* __restrict__ x2,
    const float* __restrict__ c1b, const float* __restrict__ c2b,
    const float* __restrict__ d2b, const float* __restrict__ d1b,
    const float* __restrict__ lin_w, const float* __restrict__ lin_b,
    const unsigned short* __restrict__ w1frag,
    const unsigned short* __restrict__ w2frag,
    const unsigned short* __restrict__ dw2frag,
    const float* __restrict__ dw1,
    float* __restrict__ recon)
{
    __shared__ alignas(16) char sbuf[FLDS];
    const int b   = blockIdx.x;
    const int pi  = b / FNGRP, g = b - pi * FNGRP;
    const int pj0 = 2 * g;
    const int npat = (pj0 + 1 < NH_) ? 2 : 1;
    const int n0  = pi * NH_ + pj0;
    const int n1  = (npat == 2) ? (n0 + 1) : n0;
    const int Y0  = pi * STR_, X0 = pj0 * STR_;
    const int t   = (int)threadIdx.x;
    const int wv  = t >> 6, lane = t & 63;
    const int ln15 = lane & 15, quad = lane >> 4;

    bf16x8 w1b[8];
    #pragma unroll
    for (int gg = 0; gg < 8; ++gg)
        w1b[gg] = *(const bf16x8*)(w1frag + (gg * 64 + lane) * 8);
    const float lw00 = lin_w[2 * n0], lw01 = lin_w[2 * n0 + 1];
    const float lw10 = lin_w[2 * n1], lw11 = lin_w[2 * n1 + 1];
    const float lbn0 = lin_b[n0], lbn1 = lin_b[n1];
    const float d1b0 = d1b[0];
    const f32x4 c1bq0 = *(const f32x4*)(c1b + quad * 4);
    f32x4 c1bq1 = (f32x4){0.f, 0.f, 0.f, 0.f};
    if (quad < 2) c1bq1 = *(const f32x4*)(c1b + 16 + quad * 4);
    float dwp[4] = {0.f, 0.f, 0.f, 0.f};
    {
        int r0 = t >> 5, c0 = t & 31;
        if (c0 < 24) {
            dwp[0] = dw1[(c0 * 2 + 0) * 64 + r0];
            dwp[1] = dw1[(c0 * 2 + 1) * 64 + r0];
        }
        int k1 = t + 1024, r1 = k1 >> 5, c1 = k1 & 31;
        if (c1 < 24) {
            dwp[2] = dw1[(c1 * 2 + 0) * 64 + r1];
            dwp[3] = dw1[(c1 * 2 + 1) * 64 + r1];
        }
    }

    // ---- S0: zero hazard windows; stage union patch [2][32][48] x 2 copies ----
    if (t < 4)       ((float*)(sbuf + FGAP16))[t] = 0.f;
    else if (t < 8)  ((float*)(sbuf + FSH2_1))[t - 4] = 0.f;
    else if (t < 42) ((float*)(sbuf + FZROW))[t - 8] = 0.f;     // 136B zrow
    #pragma unroll
    for (int it = 0; it < 3; ++it) {
        int k = t + it * 1024;
        int d = (k >= 1536) ? 1 : 0;
        int rem = k - d * 1536;
        int y = rem / 48, x = rem - y * 48;
        int xg = X0 + x; if (xg > W_ - 1) xg = W_ - 1;
        unsigned short bb = f2bf((d ? x2 : x1)[(Y0 + y) * W_ + xg]);
        int row = (d * 32 + y) * 48;
        ((unsigned short*)(sbuf + FCP0))[row + x] = bb;
        if (x > 0) ((unsigned short*)(sbuf + FCP1))[row + x - 1] = bb;
    }
    __syncthreads();

    // ---- S1: conv1 union grid. M=1025 linear, N=32, K=128 (16x16x32) ----
    for (int tl = wv; tl < 65; tl += 16) {
        const int rawm = tl * 16 + ln15;
        int m = rawm; if (m > 1024) m = 1024;
        int u = m / 41, v = m - u * 41;
        const char* cps = sbuf + ((v & 1) ? FCP1 : FCP0);
        const int vb2 = (v & ~1) * 2;
        f32x4 acc[2];
        acc[0] = (f32x4){0.f, 0.f, 0.f, 0.f};
        acc[1] = (f32x4){0.f, 0.f, 0.f, 0.f};
        #pragma unroll
        for (int kc = 0; kc < 4; ++kc) {
            const int idx8 = kc * 4 + quad;
            const int dd = idx8 >> 3, pp = idx8 & 7;
            const unsigned int* ap = (const unsigned int*)(cps + (dd * 32 + u + pp) * 96 + vb2);
            union { unsigned int u4[4]; bf16x8 v8; } af;
            af.u4[0] = ap[0]; af.u4[1] = ap[1]; af.u4[2] = ap[2]; af.u4[3] = ap[3];
            acc[0] = mfma_bf16(w1b[kc * 2 + 0], af.v8, acc[0]);
            acc[1] = mfma_bf16(w1b[kc * 2 + 1], af.v8, acc[1]);
        }
        if (rawm < 1025) {
            char* rowp = sbuf + rawm * 48;
            short4v p0;
            #pragma unroll
            for (int r = 0; r < 4; ++r) {
                float hv = acc[0][r] + c1bq0[r];
                hv = hv > 0.f ? hv : elu_neg(hv);
                p0[r] = (short)f2bf(hv);
            }
            *(short4v*)(rowp + quad * 8) = p0;
            if (quad < 2) {
                short4v p1;
                #pragma unroll
                for (int r = 0; r < 4; ++r) {
                    float hw = acc[1][r] + c1bq1[r];
                    hw = hw > 0.f ? hw : elu_neg(hw);
                    p1[r] = (short)f2bf(hw);
                }
                *(short4v*)(rowp + 32 + quad * 8) = p1;
            }
        }
    }
    __syncthreads();

    // ---- S2: conv2 both patches (16x16x32, unchanged math). Writeback to
    //      128B-stride SWIZZLED sH2; pad bytes [120,128) written ZERO. ----
    auto s2pass = [&](int t0, int t1) {
        const bool h1ok = (t1 < 56);
        int ab[2], loc[2], Pp[2];
        #pragma unroll
        for (int i = 0; i < 2; ++i) {
            int tt = i ? (h1ok ? t1 : t0) : t0;
            int P = (tt >= 28) ? 1 : 0;
            int lc = tt - P * 28;
            int mm = lc * 16 + ln15; if (mm > 440) mm = 440;
            int y = mm / 21, x = mm - y * 21;
            ab[i] = (y * 41 + P * 16 + x) * 48;
            loc[i] = lc; Pp[i] = P;
        }
        f32x4 acc2[2][4];
        #pragma unroll
        for (int i = 0; i < 2; ++i)
            #pragma unroll
            for (int nt = 0; nt < 4; ++nt)
                acc2[i][nt] = (f32x4){0.f, 0.f, 0.f, 0.f};
        const unsigned short* wb = w2frag + lane * 8;
        #pragma unroll
        for (int p = 0; p < 5; ++p) {
            #pragma unroll
            for (int q = 0; q < 5; ++q) {
                const int tap  = p * 5 + q;
                const int toff = (p * 41 + q) * 48;
                bf16x8 bfr[4];
                #pragma unroll
                for (int nt = 0; nt < 4; ++nt)
                    bfr[nt] = *(const bf16x8*)(wb + (tap * 4 + nt) * 512);
                {
                    bf16x8 a = *(const bf16x8*)(sbuf + ab[0] + toff + quad * 16);
                    #pragma unroll
                    for (int nt = 0; nt < 4; ++nt)
                        acc2[0][nt] = mfma_bf16(bfr[nt], a, acc2[0][nt]);
                }
                if (h1ok) {
                    bf16x8 a = *(const bf16x8*)(sbuf + ab[1] + toff + quad * 16);
                    #pragma unroll
                    for (int nt = 0; nt < 4; ++nt)
                        acc2[1][nt] = mfma_bf16(bfr[nt], a, acc2[1][nt]);
                }
            }
        }
        #pragma unroll
        for (int i = 0; i < 2; ++i) {
            if (i == 1 && !h1ok) continue;
            int rawpix = loc[i] * 16 + ln15;
            if (rawpix < 441) {
                const int rowbyte = FSH2_0 + Pp[i] * FSH2SZ + rawpix * 128;
                char* rowp = sbuf + rowbyte;
                const int sw = ((rowbyte >> 7) & 7) << 4;        // abs-addr key
                #pragma unroll
                for (int nt = 0; nt < 4; ++nt) {
                    const int goff = nt * 32 + quad * 8;
                    if (nt == 3 && quad == 3) {
                        *(short4v*)(rowp + (goff ^ sw)) = (short4v){0, 0, 0, 0};
                    } else {
                        const f32x4 bq = *(const f32x4*)(c2b + nt * 16 + quad * 4);
                        short4v pk;
                        #pragma unroll
                        for (int r = 0; r < 4; ++r)
                            pk[r] = (short)f2bf(fmaxf(acc2[i][nt][r] + bq[r], 0.f));
                        *(short4v*)(rowp + (goff ^ sw)) = pk;
                    }
                }
            }
        }
    };
    s2pass(wv, wv + 16);
    s2pass(wv + 32, wv + 48);
    __syncthreads();

    // ---- S3: deconv2 via 32x32x16 MFMA. 40 mtiles-of-32 (20/patch) over 16
    //      waves (wv<8: 3, else 2). Per tap per mtile: 4 MFMA + 4 b128 reads.
    //      acc D layout: pixel = lane&31, c = (reg&3)+8*(reg>>2)+4*(lane>>5). ----
    f32x16 acc3[3];
    {
        #pragma unroll
        for (int i = 0; i < 3; ++i)
            #pragma unroll
            for (int r = 0; r < 16; ++r) acc3[i][r] = 0.f;

        int uarr[3], varr[3], aoff[3];
        bool mval[3];
        #pragma unroll
        for (int i = 0; i < 3; ++i) {
            int t5 = wv + 16 * i;
            int P = (t5 >= 20) ? 1 : 0;
            int lc = t5 - P * 20;
            int m = lc * 32 + (lane & 31);
            mval[i] = (m < 625);
            int mc = mval[i] ? m : 0;
            uarr[i] = mc / 25; varr[i] = mc - uarr[i] * 25;
            aoff[i] = FSH2_0 + P * FSH2SZ + (uarr[i] * 21 + varr[i]) * 128;
        }
        const unsigned short* db = dw2frag + lane * 8;
        const int hh16 = (lane >> 5) * 16;
        #pragma unroll
        for (int dy = 0; dy < 5; ++dy) {
            #pragma unroll
            for (int dx = 0; dx < 5; ++dx) {
                const int tap = dy * 5 + dx;
                const int t2o = (dy * 21 + dx) * 128;
                bf16x8 bw0 = *(const bf16x8*)(db + tap * 2048);
                bf16x8 bw1 = *(const bf16x8*)(db + tap * 2048 + 512);
                bf16x8 bw2 = *(const bf16x8*)(db + tap * 2048 + 1024);
                bf16x8 bw3 = *(const bf16x8*)(db + tap * 2048 + 1536);
                #pragma unroll
                for (int i = 0; i < 3; ++i) {
                    if (i == 2 && wv >= 8) continue;             // wave-uniform
                    int yv = uarr[i] - dy, xv = varr[i] - dx;
                    bool ok = mval[i] && ((unsigned)yv < 21u) && ((unsigned)xv < 21u);
                    int ra = ok ? (aoff[i] - t2o) : FZROW;       // zeros if invalid
                    const int s = ((ra >> 7) & 7) << 4;          // abs-addr key
                    const char* bp = sbuf + ra;
                    bf16x8 a0 = *(const bf16x8*)(bp + ((0 + hh16) ^ s));
                    acc3[i] = mfma32_bf16(bw0, a0, acc3[i]);     // W=instr-A
                    bf16x8 a1 = *(const bf16x8*)(bp + ((32 + hh16) ^ s));
                    acc3[i] = mfma32_bf16(bw1, a1, acc3[i]);
                    bf16x8 a2 = *(const bf16x8*)(bp + ((64 + hh16) ^ s));
                    acc3[i] = mfma32_bf16(bw2, a2, acc3[i]);
                    bf16x8 a3 = *(const bf16x8*)(bp + ((96 + hh16) ^ s));
                    acc3[i] = mfma32_bf16(bw3, a3, acc3[i]);
                }
            }
        }
    }
    __syncthreads();

    // ---- S4a: h3 = elu(acc3 + d2b) via 32x32 D layout: each lane owns ONE
    //      pixel, channels c = g*8 + 4*hh + r (g=0..2).  3x b64 stores. ----
    float* sp = (float*)(sbuf + FSPA);
    {
        const int hh = lane >> 5;
        #pragma unroll
        for (int i = 0; i < 3; ++i) {
            if (i == 2 && wv >= 8) continue;
            int t5 = wv + 16 * i;
            int P = (t5 >= 20) ? 1 : 0;
            int lc = t5 - P * 20;
            int p = lc * 32 + (lane & 31);
            if (p < 625) {
                char* rowp = sbuf + P * FH3SZ + p * 48;
                #pragma unroll
                for (int gg2 = 0; gg2 < 3; ++gg2) {
                    const int c0 = gg2 * 8 + hh * 4;
                    const f32x4 bq = *(const f32x4*)(d2b + c0);
                    short4v pk;
                    #pragma unroll
                    for (int r = 0; r < 4; ++r) {
                        float hv = acc3[i][gg2 * 4 + r] + bq[r];
                        hv = hv > 0.f ? hv : elu_neg(hv);
                        pk[r] = (short)f2bf(hv);
                    }
                    *(short4v*)(rowp + c0 * 2) = pk;
                }
            }
        }
    }
    {
        int r0 = t >> 5, c0 = t & 31;
        ((unsigned short*)(sbuf + FSWC0))[r0 * 32 + c0] = f2bf(lw00 * dwp[0] + lw01 * dwp[1]);
        ((unsigned short*)(sbuf + FSWC1))[r0 * 32 + c0] = f2bf(lw10 * dwp[0] + lw11 * dwp[1]);
        int k1 = t + 1024, r1 = k1 >> 5, c1 = k1 & 31;
        ((unsigned short*)(sbuf + FSWC0))[r1 * 32 + c1] = f2bf(lw00 * dwp[2] + lw01 * dwp[3]);
        ((unsigned short*)(sbuf + FSWC1))[r1 * 32 + c1] = f2bf(lw10 * dwp[2] + lw11 * dwp[3]);
    }
    sp[t] = 0.f; sp[t + 1024] = 0.f;
    __syncthreads();

    // ---- S4b: epilogue GEMM (16x16 path, unchanged) ----
    {
        int qoff[4];
        #pragma unroll
        for (int r = 0; r < 4; ++r) {
            int qr = quad * 4 + r;
            qoff[r] = (qr >> 3) * 32 + (qr & 7);
        }
        #pragma unroll
        for (int i = 0; i < 5; ++i) {
            int t5 = wv + 16 * i;
            int P = (t5 >= 40) ? 1 : 0;
            int lc = t5 - P * 40;
            int rawpix = lc * 16 + ln15;
            bool pok = (rawpix < 625);
            int pc = pok ? rawpix : 624;
            bf16x8 a = *(const bf16x8*)(sbuf + P * FH3SZ + pc * 48 + quad * 16);
            const char* swc = sbuf + (P ? FSWC1 : FSWC0);
            float* spP = sp + P * 1024;
            int uvbase = (pc / 25) * 32 + (pc % 25);
            #pragma unroll
            for (int nt = 0; nt < 4; ++nt) {
                bf16x8 wbv = *(const bf16x8*)(swc + (nt * 16 + ln15) * 64 + quad * 16);
                f32x4 acc4 = (f32x4){0.f, 0.f, 0.f, 0.f};
                acc4 = mfma_bf16(wbv, a, acc4);
                if (pok) {
                    #pragma unroll
                    for (int r = 0; r < 4; ++r)
                        atomicAdd(&spP[uvbase + nt * 64 + qoff[r]], acc4[r]);
                }
            }
        }
    }
    __syncthreads();

    // ---- S5: overlap-add into global recon ----
    {
        int yy = t >> 5, xx = t & 31;
        float ob0 = d1b0 * (lw00 + lw01) + lbn0;
        atomicAdd(&recon[(Y0 + yy) * W_ + X0 + xx], sp[t] + ob0);
        if (npat == 2) {
            float ob1 = d1b0 * (lw10 + lw11) + lbn1;
            atomicAdd(&recon[(Y0 + yy) * W_ + X0 + 16 + xx], sp[t + 1024] + ob1);
        }
    }
}

// ---------------------------------------------------------------------------
// Prep.  conv1/conv2 unchanged.  deconv2 REPACKED for 32x32x16 instr-A:
//   i = tap*2048 + ks*512 + lane*8 + j
//   c = lane&31 (M rows, zero c>=24); k = ks*16 + (lane>>5)*8 + j (zero k>=60)
// ---------------------------------------------------------------------------
__global__ void prep_kernel(const float* __restrict__ c1w,
                            const float* __restrict__ c2w,
                            const float* __restrict__ d2w,
                            unsigned short* __restrict__ w1frag,
                            unsigned short* __restrict__ w2frag,
                            unsigned short* __restrict__ dw2frag)
{
    int i = blockIdx.x * blockDim.x + threadIdx.x;
    if (i < 51200) {
        int j = i & 7, lane = (i >> 3) & 63;
        int ln15 = lane & 15, quad = lane >> 4;
        if (i < 4096) {   // conv1
            int g = i >> 9;
            int kc = g >> 1, nt = g & 1;
            int nn = nt * 16 + ln15, k = kc * 32 + quad * 8 + j;
            w1frag[i] = f2bf((nn < 24) ? c1w[nn * 128 + k] : 0.f);
        }
        {   // conv2 (16x16x32 packing, unchanged)
            int nt = (i >> 9) & 3, tap = i >> 11;
            int o = nt * 16 + ln15, c = quad * 8 + j;
            float v = (o < 60 && c < 24) ? c2w[(o * 24 + c) * 25 + tap] : 0.f;
            w2frag[i] = f2bf(v);
        }
        {   // deconv2 (NEW 32x32x16 packing)
            int ks = (i >> 9) & 3, tap = i >> 11;
            int k = ks * 16 + (lane >> 5) * 8 + j, c = lane & 31;
            float v = (k < 60 && c < 24) ? d2w[(k * 24 + c) * 25 + tap] : 0.f;
            dw2frag[i] = f2bf(v);
        }
    }
}

__global__ void finalize_kernel(const float* __restrict__ x2,
                                const float* __restrict__ l1w,
                                float* __restrict__ out)
{
    int i = blockIdx.x * blockDim.x + threadIdx.x;
    if (i < H_ * W_) {
        float r = out[i];
        out[i] = x2[i] - r * l1w[0];
    }
}

extern "C" void kernel_launch(void* const* d_in, const int* in_sizes, int n_in,
                              void* d_out, int out_size, void* d_ws, size_t ws_size,
                              hipStream_t stream)
{
    const float* x1  = (const float*)d_in[0];
    const float* x2  = (const float*)d_in[1];
    const float* c1w = (const float*)d_in[2];
    const float* c1b = (const float*)d_in[3];
    const float* c2w = (const float*)d_in[4];
    const float* c2b = (const float*)d_in[5];
    const float* d2w = (const float*)d_in[6];
    const float* d2b = (const float*)d_in[7];
    const float* d1w = (const float*)d_in[8];
    const float* d1b = (const float*)d_in[9];
    const float* lw  = (const float*)d_in[10];
    const float* lb  = (const float*)d_in[11];
    const float* l1w = (const float*)d_in[12];

    float*          out     = (float*)d_out;
    unsigned short* w1frag  = (unsigned short*)d_ws;                      // 8192 B
    unsigned short* w2frag  = (unsigned short*)((char*)d_ws + 8192);      // 102400 B
    unsigned short* dw2frag = (unsigned short*)((char*)d_ws + 110592);    // 102400 B

    hipMemsetAsync(d_out, 0, (size_t)H_ * W_ * sizeof(float), stream);
    prep_kernel<<<100, 512, 0, stream>>>(c1w, c2w, d2w, w1frag, w2frag, dw2frag);
    fused_patch_kernel<<<FNBLK, 1024, 0, stream>>>(x1, x2, c1b, c2b, d2b, d1b,
                                                   lw, lb, w1frag, w2frag, dw2frag,
                                                   d1w, out);
    finalize_kernel<<<(H_ * W_ + 255) / 256, 256, 0, stream>>>(x2, l1w, out);
}